// Round 6
// baseline (100.650 us; speedup 1.0000x reference)
//
#include <hip/hip_runtime.h>

// out[i, j] = x[i, j] * a[j];  x: [65536, 1024] f32, a: [1024] f32.
//
// Counter-driven design (R4/R5 profiles):
//  - x (256 MiB) ~half-hits the 256 MiB Infinity Cache; out's allocations
//    were evicting x -> NONTEMPORAL STORES keep out from displacing x
//    (R5: 130 -> 85.8 us). Loads stay cached (nt loads regressed, R3).
//  - MLP: 2 CONSECUTIVE float4 per thread (32 B/lane, wave = dense 2 KiB
//    segment) -> 2 independent loads in flight. R4's stride-SEPARATED
//    unroll scattered each wave's writes 8 MiB apart and regressed; this
//    one keeps the footprint dense.
//  - Scale hoisted to registers: pair-stride (2048*256) is a multiple of
//    128 pairs -> both column-quads per thread are loop-invariant.
//  - 32-bit index math (byte offsets fit uint32 at 256 MiB).

#define XSIZE 1024
#define XSIZE4 (XSIZE / 4)   // 256 float4 column-quads

typedef float f4 __attribute__((ext_vector_type(4)));

__global__ __launch_bounds__(256) void ic_adjust_kernel(
    const float* __restrict__ x,
    const float* __restrict__ a,
    float* __restrict__ out,
    int n2) {                 // number of float4-PAIRS (32B units)
    const f4* __restrict__ x4 = reinterpret_cast<const f4*>(x);
    const f4* __restrict__ a4 = reinterpret_cast<const f4*>(a);
    f4* __restrict__ o4 = reinterpret_cast<f4*>(out);

    const int tid = blockIdx.x * blockDim.x + threadIdx.x;
    const int stride = gridDim.x * blockDim.x;

    // Pair p covers f4 indices 2p, 2p+1. stride % 128 == 0 so the two
    // column-quads are invariant across the grid-stride loop.
    const f4 s0 = a4[(2 * tid) & (XSIZE4 - 1)];
    const f4 s1 = a4[(2 * tid + 1) & (XSIZE4 - 1)];

    for (int p = tid; p < n2; p += stride) {
        const int i = 2 * p;
        f4 v0 = x4[i];          // two adjacent 16B loads, both in flight
        f4 v1 = x4[i + 1];
        v0 *= s0;
        v1 *= s1;
        __builtin_nontemporal_store(v0, &o4[i]);
        __builtin_nontemporal_store(v1, &o4[i + 1]);
    }
}

extern "C" void kernel_launch(void* const* d_in, const int* in_sizes, int n_in,
                              void* d_out, int out_size, void* d_ws, size_t ws_size,
                              hipStream_t stream) {
    const float* x = (const float*)d_in[0];
    const float* a = (const float*)d_in[1];
    float* out = (float*)d_out;

    const int n2 = out_size / 8;  // 8,388,608 float4-pairs (32B units)

    const int block = 256;
    int blocks_needed = (n2 + block - 1) / block;
    int grid = (blocks_needed < 2048) ? blocks_needed : 2048;

    ic_adjust_kernel<<<grid, block, 0, stream>>>(x, a, out, n2);
}

// Round 7
// 82.303 us; speedup vs baseline: 1.2229x; 1.2229x over previous
//
#include <hip/hip_runtime.h>

// out[i, j] = x[i, j] * a[j];  x: [65536, 1024] f32, a: [1024] f32.
//
// Counter-driven design (R4/R5/R6 profiles):
//  - NONTEMPORAL STORES keep out from evicting x in L3 (R5: 130 -> 85.8us).
//    Loads stay cached (nt loads regressed, R3).
//  - nt stores MUST be per-instruction contiguous: R6's lane-interleaved
//    pair stores caused +15% WRITE_SIZE amplification (half-filled HBM
//    granules). Here every load/store is a dense 1 KiB wave segment.
//  - MLP via block-dense x2 unroll: each block owns two ADJACENT 4 KiB
//    chunks (thread handles i and i+256). 2 independent loads in flight,
//    8 KiB dense footprint per block-iteration.
//  - Offset 256 == 0 mod 256 column-quads -> ONE scale register covers
//    both accesses; no LDS, no lgkmcnt in hot loop.
//  - 32-bit index math (byte offsets fit uint32 at 256 MiB).

#define XSIZE 1024
#define XSIZE4 (XSIZE / 4)   // 256 float4 column-quads

typedef float f4 __attribute__((ext_vector_type(4)));

__global__ __launch_bounds__(256) void ic_adjust_kernel(
    const float* __restrict__ x,
    const float* __restrict__ a,
    float* __restrict__ out,
    int n4) {
    const f4* __restrict__ x4 = reinterpret_cast<const f4*>(x);
    const f4* __restrict__ a4 = reinterpret_cast<const f4*>(a);
    f4* __restrict__ o4 = reinterpret_cast<f4*>(out);

    const int B = blockDim.x;  // 256
    // Block b owns chunks [2b*B, 2b*B + 2B); grid-stride by 2*grid*B.
    const int start = 2 * blockIdx.x * B + threadIdx.x;
    const int stride = 2 * gridDim.x * B;

    // Both accesses (i, i+B) have column-quad tid & 255 (2b*B == 0 mod 256,
    // B == 256): one loop-invariant scale register.
    const f4 s = a4[threadIdx.x & (XSIZE4 - 1)];

    for (int i = start; i + (int)blockDim.x < n4; i += stride) {
        f4 v0 = x4[i];        // two contiguous-1KiB wave loads in flight
        f4 v1 = x4[i + B];
        v0 *= s;
        v1 *= s;
        __builtin_nontemporal_store(v0, &o4[i]);      // dense 1KiB segments
        __builtin_nontemporal_store(v1, &o4[i + B]);
    }
}

extern "C" void kernel_launch(void* const* d_in, const int* in_sizes, int n_in,
                              void* d_out, int out_size, void* d_ws, size_t ws_size,
                              hipStream_t stream) {
    const float* x = (const float*)d_in[0];
    const float* a = (const float*)d_in[1];
    float* out = (float*)d_out;

    const int n4 = out_size / 4;  // 16,777,216 float4s

    const int block = 256;
    // Each block-iteration covers 2*block float4s.
    int blocks_needed = (n4 + 2 * block - 1) / (2 * block);
    int grid = (blocks_needed < 2048) ? blocks_needed : 2048;

    ic_adjust_kernel<<<grid, block, 0, stream>>>(x, a, out, n4);
}

// Round 8
// 82.250 us; speedup vs baseline: 1.2237x; 1.0007x over previous
//
#include <hip/hip_runtime.h>

// out[i, j] = x[i, j] * a[j];  x: [65536, 1024] f32, a: [1024] f32.
//
// Counter-driven design (R4-R7 profiles):
//  - NONTEMPORAL STORES keep out from evicting x in L3 (R5: 130 -> 85.8us).
//    Loads stay cached (nt loads regressed, R3).
//  - nt stores MUST be per-instruction contiguous (R6: lane-interleaved
//    stores -> +15% WRITE_SIZE amplification). Every access here is a
//    dense 1 KiB wave segment.
//  - Block-dense unroll is the only unroll shape that helps (R7: x2 ->
//    85.8 -> 82.3us). Extend to x4: each block owns four ADJACENT 4 KiB
//    chunks (thread handles i, i+256, i+512, i+768) -> 4 independent
//    loads in flight, 16 KiB dense footprint, 8 grid-stride iterations.
//  - Offsets are multiples of 256 quads -> ONE loop-invariant scale
//    register; no LDS, no lgkmcnt in hot loop.
//  - 32-bit index math (byte offsets fit uint32 at 256 MiB).

#define XSIZE 1024
#define XSIZE4 (XSIZE / 4)   // 256 float4 column-quads

typedef float f4 __attribute__((ext_vector_type(4)));

__global__ __launch_bounds__(256) void ic_adjust_kernel(
    const float* __restrict__ x,
    const float* __restrict__ a,
    float* __restrict__ out,
    int n4) {
    const f4* __restrict__ x4 = reinterpret_cast<const f4*>(x);
    const f4* __restrict__ a4 = reinterpret_cast<const f4*>(a);
    f4* __restrict__ o4 = reinterpret_cast<f4*>(out);

    constexpr int B = 256;   // block size
    constexpr int U = 4;     // chunks per block per iteration
    // Block b owns chunks [U*b*B, U*b*B + U*B); grid-stride by U*grid*B.
    const int start = U * blockIdx.x * B + threadIdx.x;
    const int stride = U * gridDim.x * B;

    // All U accesses have column-quad tid & 255 (offsets are multiples of
    // 256): one loop-invariant scale register.
    const f4 s = a4[threadIdx.x & (XSIZE4 - 1)];

    for (int i = start; i + (U - 1) * B < n4; i += stride) {
        f4 v0 = x4[i];            // four contiguous-1KiB wave loads in flight
        f4 v1 = x4[i + B];
        f4 v2 = x4[i + 2 * B];
        f4 v3 = x4[i + 3 * B];
        v0 *= s;
        v1 *= s;
        v2 *= s;
        v3 *= s;
        __builtin_nontemporal_store(v0, &o4[i]);        // dense 1KiB segments
        __builtin_nontemporal_store(v1, &o4[i + B]);
        __builtin_nontemporal_store(v2, &o4[i + 2 * B]);
        __builtin_nontemporal_store(v3, &o4[i + 3 * B]);
    }
}

extern "C" void kernel_launch(void* const* d_in, const int* in_sizes, int n_in,
                              void* d_out, int out_size, void* d_ws, size_t ws_size,
                              hipStream_t stream) {
    const float* x = (const float*)d_in[0];
    const float* a = (const float*)d_in[1];
    float* out = (float*)d_out;

    const int n4 = out_size / 4;  // 16,777,216 float4s

    const int block = 256;
    // Each block-iteration covers 4*block float4s.
    int blocks_needed = (n4 + 4 * block - 1) / (4 * block);
    int grid = (blocks_needed < 2048) ? blocks_needed : 2048;

    ic_adjust_kernel<<<grid, block, 0, stream>>>(x, a, out, n4);
}